// Round 8
// baseline (243.226 us; speedup 1.0000x reference)
//
#include <hip/hip_runtime.h>

#define NB 4
#define NH 16
#define NSQ 1024
#define NSKV 1024
#define ND 64

typedef __attribute__((ext_vector_type(8))) short short8;
typedef __attribute__((ext_vector_type(4))) short short4v;
typedef __attribute__((ext_vector_type(4))) float f32x4;
typedef __attribute__((ext_vector_type(4))) int int4v;
typedef __attribute__((ext_vector_type(4))) unsigned int uint4v;
typedef __attribute__((ext_vector_type(2))) unsigned int uint2v;

__device__ __forceinline__ unsigned int cvt_pk(float lo, float hi) {
  unsigned int r;
  asm("v_cvt_pk_bf16_f32 %0, %1, %2" : "=v"(r) : "v"(lo), "v"(hi));
  return r;
}
__device__ __forceinline__ unsigned short f2bf(float f) {
  unsigned int u = __float_as_uint(f);
  u += 0x7FFFu + ((u >> 16) & 1u);
  return (unsigned short)(u >> 16);
}
__device__ __forceinline__ float bf2f(unsigned short h) {
  return __uint_as_float(((unsigned int)h) << 16);
}
__device__ __forceinline__ void lgkm0() {
  asm volatile("s_waitcnt lgkmcnt(0)" ::: "memory");
}

// 256 threads = 4 waves, each wave owns the SAME 16 q-rows but a PRIVATE
// kv-quarter [w*256, w*256+256). Wave-private K/V staging => ZERO barriers
// in the sweep (wave-local lgkm fences + counted-vmcnt chunk-ahead prefetch).
// LDS 68.25KB => 2 independent blocks/CU (store-epilogue of one block
// overlaps the read-sweep of the other).
// SWAPPED QK^T: mfma(A=K,B=Q) -> lane (lg,lm) holds P[q=lm][kv=sub*16+lg*4+j];
// A/M are float4/int4 at exactly those spots. V staged in R6-PROVEN
// transposed+padded+swizzled Vt (scalar writes, conflict-light b128 reads).
__global__ __launch_bounds__(256, 2)
void attn_fused(const float* __restrict__ Q, const float* __restrict__ K,
                const float* __restrict__ V, const int* __restrict__ M,
                const float* __restrict__ A, float* __restrict__ Octx,
                float* __restrict__ Ow)
{
  __shared__ unsigned short Ps[16 * 1024];                 // 32 KB, rows 2048B, XOR (row<<4)
  __shared__ __align__(16) unsigned short Ks[4][32 * 64];  // 16 KB; CtxS overlay post-sweep
  __shared__ __align__(16) unsigned short Vt[4][64 * 40];  // 20 KB, [d][kv] pad 80B, XOR swz
  __shared__ float SumS[16][4];

  const int t  = threadIdx.x;
  const int w  = t >> 6;
  const int l  = t & 63;
  const int lg = l >> 4;
  const int lm = l & 15;

  // XCD swizzle: same-bh blocks land on one XCD (K/V stay L2-resident)
  const int bid = blockIdx.x;
  const int bh  = (bid & 7) + ((bid >> 9) << 3);
  const int qt  = (bid >> 3) & 63;
  const int b   = bh >> 4;
  const int q0  = qt * 16;
  const int kvq = w * 256;   // this wave's kv quarter

  const float* Qp = Q + (size_t)bh * NSQ * ND;
  const float* Kp = K + (size_t)bh * NSKV * ND;
  const float* Vp = V + (size_t)bh * NSKV * ND;
  const float* Ap = A + (size_t)bh * NSQ * NSKV;
  const int*   Mp = M + (size_t)b  * NSQ * NSKV;

  unsigned short* Ksw = Ks[w];
  unsigned short* Vtw = Vt[w];

  const float C = 0.18033688011112042f;  // 0.125 * log2(e)

  // Q fragment (B operand): lane holds Q[q0+lm][dc*32+lg*8+e]
  short8 qf[2];
  {
    const float* qr = Qp + (size_t)(q0 + lm) * ND + lg * 8;
    #pragma unroll
    for (int dc = 0; dc < 2; ++dc) {
      f32x4 x = *(const f32x4*)(qr + dc * 32);
      f32x4 y = *(const f32x4*)(qr + dc * 32 + 4);
      uint4v u;
      u[0] = cvt_pk(x[0], x[1]); u[1] = cvt_pk(x[2], x[3]);
      u[2] = cvt_pk(y[0], y[1]); u[3] = cvt_pk(y[2], y[3]);
      qf[dc] = __builtin_bit_cast(short8, u);
    }
  }

  f32x4 ctx[4];
  #pragma unroll
  for (int i = 0; i < 4; ++i) ctx[i] = (f32x4){0.f, 0.f, 0.f, 0.f};
  float sum = 0.f;

  f32x4 sk[8], sv[8];                    // staging regs (one chunk in flight)
  f32x4 aA[2], aB[2];  int4v mA[2], mB[2];

  auto issueStage = [&](int kv0) {       // 32x64 f32 chunk, fully contiguous
    const float* kb = Kp + (size_t)kv0 * ND + l * 4;
    const float* vb = Vp + (size_t)kv0 * ND + l * 4;
    #pragma unroll
    for (int i = 0; i < 8; ++i) {
      sk[i] = *(const f32x4*)(kb + i * 256);
      sv[i] = *(const f32x4*)(vb + i * 256);
    }
  };
  auto loadAM = [&](int kv0, f32x4* a, int4v* m) {
    #pragma unroll
    for (int sub = 0; sub < 2; ++sub) {
      size_t off = (size_t)(q0 + lm) * NSKV + kv0 + sub * 16 + lg * 4;
      a[sub] = *(const f32x4*)(Ap + off);
      m[sub] = *(const int4v*)(Mp + off);
    }
  };
  // thread holds K/V[row=i*4+(l>>4)][(l&15)*4 + 0..3]; K -> b64 swizzled rows,
  // V -> transposed scalar writes (R6-proven formulas, chunk-local kv)
  auto writeStage = [&]() {
    #pragma unroll
    for (int i = 0; i < 8; ++i) {
      int row = i * 4 + (l >> 4);
      uint2v ku;
      ku[0] = cvt_pk(sk[i][0], sk[i][1]); ku[1] = cvt_pk(sk[i][2], sk[i][3]);
      *(uint2v*)((char*)Ksw + row * 128 + (((l & 15) * 8) ^ ((row & 7) << 4))) = ku;
      #pragma unroll
      for (int j = 0; j < 4; ++j) {
        int d = (l & 15) * 4 + j;
        *(unsigned short*)((char*)Vtw + d * 80 +
                           ((row * 2) ^ (((d >> 2) & 3) << 4))) = f2bf(sv[i][j]);
      }
    }
  };

  auto compute = [&](int kv0, const f32x4* a, const int4v* m) {
    const int ksw = (lm & 7) << 4;
    const int vsw = ((lm >> 2) & 3) << 4;
    short8 kf[4];
    #pragma unroll
    for (int sub = 0; sub < 2; ++sub)
      #pragma unroll
      for (int dc = 0; dc < 2; ++dc)
        kf[sub * 2 + dc] = *(const short8*)(
            (const char*)Ksw + (sub * 16 + lm) * 128 + ((dc * 64 + lg * 16) ^ ksw));
    short8 vf[4];
    #pragma unroll
    for (int ds = 0; ds < 4; ++ds)
      vf[ds] = *(const short8*)(
          (const char*)Vtw + (ds * 16 + lm) * 80 + ((lg * 16) ^ vsw));

    // QK^T (A=K,B=Q): acc[j] = logit(q=lm, kv=kv0+sub*16+lg*4+j)
    #pragma unroll
    for (int sub = 0; sub < 2; ++sub) {
      f32x4 acc = (f32x4){0.f, 0.f, 0.f, 0.f};
      #pragma unroll
      for (int dc = 0; dc < 2; ++dc)
        acc = __builtin_amdgcn_mfma_f32_16x16x32_bf16(kf[sub * 2 + dc], qf[dc],
                                                      acc, 0, 0, 0);
      float pe[4];
      #pragma unroll
      for (int j = 0; j < 4; ++j) {
        float amc = m[sub][j] ? a[sub][j] * C : -1.8e8f;
        pe[j] = exp2f(fmaf(acc[j], C, amc));   // masked -> exact 0
        sum += pe[j];
      }
      uint2v u2;
      u2[0] = cvt_pk(pe[0], pe[1]); u2[1] = cvt_pk(pe[2], pe[3]);
      *(uint2v*)((char*)Ps + lm * 2048 +
                 (((kv0 + sub * 16 + lg * 4) * 2) ^ (lm << 4))) = u2;
    }
    // own-wave Ps RAW fence (rule #18)
    lgkm0();
    __builtin_amdgcn_sched_barrier(0);
    // PV: pf = P[q=lm][kv0+lg*8..+7]
    short8 pf = *(const short8*)((const char*)Ps + lm * 2048 +
                                 (((kv0 + lg * 8) * 2) ^ (lm << 4)));
    #pragma unroll
    for (int ds = 0; ds < 4; ++ds)
      ctx[ds] = __builtin_amdgcn_mfma_f32_16x16x32_bf16(pf, vf[ds], ctx[ds], 0, 0, 0);
  };

  // ---- barrier-free sweep: 8 chunks of 32 kv in this wave's quarter ----
  issueStage(kvq);
  loadAM(kvq, aA, mA);
  for (int c = 0; c < 8; c += 2) {
    int kv0 = kvq + c * 32;
    loadAM(kvq + ((c + 1) & 7) * 32, aB, mB);   // HBM stream, a chunk ahead
    writeStage();                                // counted-vmcnt wait on sk/sv
    issueStage(kvq + ((c + 1) & 7) * 32);        // next chunk in flight
    lgkm0();                                     // staging visible (own wave)
    compute(kv0, aA, mA);
    loadAM(kvq + ((c + 2) & 7) * 32, aA, mA);
    writeStage();
    issueStage(kvq + ((c + 2) & 7) * 32);
    lgkm0();
    compute(kv0 + 32, aB, mB);
  }

  // ---- merge quarters ----
  sum += __shfl_xor(sum, 16);
  sum += __shfl_xor(sum, 32);
  if (l < 16) SumS[l][w] = sum;
  __syncthreads();                       // ALL sweeps complete -> Ks is dead

  float (*CtxS)[16][64] = (float(*)[16][64])(&Ks[0][0]);   // 12 KB overlay
  if (w) {
    #pragma unroll
    for (int ds = 0; ds < 4; ++ds)
      #pragma unroll
      for (int j = 0; j < 4; ++j)
        CtxS[w - 1][lg * 4 + j][ds * 16 + lm] = ctx[ds][j];
  }
  __syncthreads();

  float rcpv = 0.f;
  if (l < 16)
    rcpv = 1.0f / (SumS[l][0] + SumS[l][1] + SumS[l][2] + SumS[l][3]);

  if (w == 0) {
    #pragma unroll
    for (int ds = 0; ds < 4; ++ds)
      #pragma unroll
      for (int j = 0; j < 4; ++j) {
        int qr = lg * 4 + j;
        float rc = __shfl(rcpv, qr);
        float v = ctx[ds][j] + CtxS[0][qr][ds * 16 + lm] +
                  CtxS[1][qr][ds * 16 + lm] + CtxS[2][qr][ds * 16 + lm];
        Octx[((size_t)bh * NSQ + q0 + qr) * ND + ds * 16 + lm] = v * rc;
      }
  }

  // ---- weights out: each wave stores its own quarter, f32x4-coalesced ----
  float* Owp = Ow + (size_t)bh * NSQ * NSKV + (size_t)q0 * NSKV + kvq;
  for (int r = 0; r < 16; ++r) {
    float rr = __shfl(rcpv, r);
    short4v p = *(const short4v*)((const char*)Ps + r * 2048 +
                                  (((kvq + l * 4) * 2) ^ (r << 4)));
    f32x4 o;
    o[0] = bf2f((unsigned short)p[0]) * rr;
    o[1] = bf2f((unsigned short)p[1]) * rr;
    o[2] = bf2f((unsigned short)p[2]) * rr;
    o[3] = bf2f((unsigned short)p[3]) * rr;
    *(f32x4*)&Owp[(size_t)r * NSKV + l * 4] = o;
  }
}

extern "C" void kernel_launch(void* const* d_in, const int* in_sizes, int n_in,
                              void* d_out, int out_size, void* d_ws, size_t ws_size,
                              hipStream_t stream) {
  const float* Q = (const float*)d_in[0];
  const float* K = (const float*)d_in[1];
  const float* V = (const float*)d_in[2];
  const int*   M = (const int*)d_in[3];
  const float* A = (const float*)d_in[4];
  float* ctx = (float*)d_out;
  float* wts = ctx + (size_t)NB * NH * NSQ * ND;  // outputs: (context, weights)
  dim3 grid(NB * NH * (NSQ / 16));                // 4096 blocks
  attn_fused<<<grid, dim3(256), 0, stream>>>(Q, K, V, M, A, ctx, wts);
}

// Round 9
// 222.719 us; speedup vs baseline: 1.0921x; 1.0921x over previous
//
#include <hip/hip_runtime.h>

#define NB 4
#define NH 16
#define NSQ 1024
#define NSKV 1024
#define ND 64

typedef __attribute__((ext_vector_type(8))) short short8;
typedef __attribute__((ext_vector_type(4))) float f32x4;
typedef __attribute__((ext_vector_type(4))) int int4v;
typedef __attribute__((ext_vector_type(4))) unsigned int uint4v;
typedef __attribute__((ext_vector_type(2))) unsigned int uint2v;

__device__ __forceinline__ unsigned int cvt_pk(float lo, float hi) {
  unsigned int r;
  asm("v_cvt_pk_bf16_f32 %0, %1, %2" : "=v"(r) : "v"(lo), "v"(hi));
  return r;
}
__device__ __forceinline__ unsigned short f2bf(float f) {
  unsigned int u = __float_as_uint(f);
  u += 0x7FFFu + ((u >> 16) & 1u);
  return (unsigned short)(u >> 16);
}
__device__ __forceinline__ float bf2f(unsigned short h) {
  return __uint_as_float(((unsigned int)h) << 16);
}
__device__ __forceinline__ void bar() { __builtin_amdgcn_s_barrier(); }
__device__ __forceinline__ void lgkm0() {
  asm volatile("s_waitcnt lgkmcnt(0)" ::: "memory");
}

// R6 structure at HALF size so 2 blocks/CU fit (LDS exactly 80 KB):
// 256 threads = 4 waves: p = w&1 -> q-rows [q0+p*16, +16); h = w>>1 -> kv
// half [h*512, +512). The 2 waves of a half gang-stage its K/V chunks with
// fully-contiguous loads (R6-proven). Sibling BLOCK on the CU absorbs the
// barrier stalls that R6 exposed (1 block/CU there).
// SWAPPED QK^T: mfma(A=K,B=Q) -> lane (lg,lm) holds P[q=lm][kv=sub*16+lg*4+j].
// A/M float4/int4 at those spots, prefetched a full chunk ahead.
// Vt: [d(64)][64B] rows, slot-XOR ((d>>1)&3)<<4 (bijective, ~2-way reads).
__global__ __launch_bounds__(256, 2)
void attn_fused(const float* __restrict__ Q, const float* __restrict__ K,
                const float* __restrict__ V, const int* __restrict__ M,
                const float* __restrict__ A, float* __restrict__ Octx,
                float* __restrict__ Ow)
{
  __shared__ __align__(16) unsigned char LDS[81920];   // 80 KB exactly
  unsigned short* Ps = (unsigned short*)LDS;           // [32][1024] bf16, rows 2048B

  const int t  = threadIdx.x;
  const int w  = t >> 6;
  const int l  = t & 63;
  const int lg = l >> 4;
  const int lm = l & 15;
  const int p  = w & 1;        // q-row pair
  const int h  = w >> 1;       // kv half
  const int g  = p * 64 + l;   // gang lane within half (0..127)

  // XCD swizzle: same-bh blocks cluster on one XCD (K/V stay L2-resident)
  const int bid = blockIdx.x;
  const int y   = bid >> 3;
  const int qt  = y & 31;                  // 32 q-tiles of 32 rows
  const int bh  = (bid & 7) * 8 + (y >> 5);
  const int b   = bh >> 4;
  const int q0  = qt * 32;
  const int kvb = h * 512;

  unsigned char* KsH = LDS + 65536 + h * 4096;   // [32 rows][128B], XOR (row&7)<<4
  unsigned char* VtH = LDS + 73728 + h * 4096;   // [64 d][64B], XOR ((d>>1)&3)<<4

  const float* Qp = Q + (size_t)bh * NSQ * ND;
  const float* Kp = K + (size_t)bh * NSKV * ND;
  const float* Vp = V + (size_t)bh * NSKV * ND;
  const float* Ap = A + (size_t)bh * NSQ * NSKV;
  const int*   Mp = M + (size_t)b  * NSQ * NSKV;

  const float C = 0.18033688011112042f;  // 0.125 * log2(e)

  // Q fragment (B operand): lane holds Q[q0+p*16+lm][dc*32+lg*8+e]
  short8 qf[2];
  {
    const float* qr = Qp + (size_t)(q0 + p * 16 + lm) * ND + lg * 8;
    #pragma unroll
    for (int dc = 0; dc < 2; ++dc) {
      f32x4 x = *(const f32x4*)(qr + dc * 32);
      f32x4 y2 = *(const f32x4*)(qr + dc * 32 + 4);
      uint4v u;
      u[0] = cvt_pk(x[0], x[1]); u[1] = cvt_pk(x[2], x[3]);
      u[2] = cvt_pk(y2[0], y2[1]); u[3] = cvt_pk(y2[2], y2[3]);
      qf[dc] = __builtin_bit_cast(short8, u);
    }
  }

  f32x4 ctx[4];
  #pragma unroll
  for (int i = 0; i < 4; ++i) ctx[i] = (f32x4){0.f, 0.f, 0.f, 0.f};
  float sum = 0.f;

  f32x4 skA[4], svA[4], skB[4], svB[4];      // gang staging, chunk in flight
  f32x4 aA[2], aB[2];  int4v mA[2], mB[2];   // A/M a chunk ahead

  // 32 kv x 64 d chunk = 2048 f32, contiguous; gang lane g takes g*4 + i*512
  auto issueStage = [&](int kv0, f32x4* sk, f32x4* sv) {
    const float* kb = Kp + (size_t)kv0 * ND + g * 4;
    const float* vb = Vp + (size_t)kv0 * ND + g * 4;
    #pragma unroll
    for (int i = 0; i < 4; ++i) {
      sk[i] = *(const f32x4*)(kb + i * 512);
      sv[i] = *(const f32x4*)(vb + i * 512);
    }
  };
  auto loadAM = [&](int kv0, f32x4* a, int4v* m) {
    #pragma unroll
    for (int sub = 0; sub < 2; ++sub) {
      size_t off = (size_t)(q0 + p * 16 + lm) * NSKV + kv0 + sub * 16 + lg * 4;
      a[sub] = *(const f32x4*)(Ap + off);
      m[sub] = *(const int4v*)(Mp + off);
    }
  };
  auto writeStage = [&](const f32x4* sk, const f32x4* sv) {
    #pragma unroll
    for (int i = 0; i < 4; ++i) {
      int f   = g * 4 + i * 512;
      int row = f >> 6;            // kv-local 0..31
      int c0  = f & 63;            // d base (multiple of 4)
      uint2v ku;
      ku[0] = cvt_pk(sk[i][0], sk[i][1]); ku[1] = cvt_pk(sk[i][2], sk[i][3]);
      *(uint2v*)(KsH + row * 128 + ((c0 * 2) ^ ((row & 7) << 4))) = ku;
      #pragma unroll
      for (int j = 0; j < 4; ++j) {
        int d = c0 + j;
        *(unsigned short*)(VtH + d * 64 + ((row * 2) ^ (((d >> 1) & 3) << 4))) =
            f2bf(sv[i][j]);
      }
    }
  };

  auto compute = [&](int kv0, const f32x4* a, const int4v* m) {
    const int ksw = (lm & 7) << 4;
    const int vsw = ((lm >> 1) & 3) << 4;
    short8 kf[4];
    #pragma unroll
    for (int sub = 0; sub < 2; ++sub)
      #pragma unroll
      for (int dc = 0; dc < 2; ++dc)
        kf[sub * 2 + dc] = *(const short8*)(
            KsH + (sub * 16 + lm) * 128 + ((dc * 64 + lg * 16) ^ ksw));
    short8 vf[4];
    #pragma unroll
    for (int ds = 0; ds < 4; ++ds)
      vf[ds] = *(const short8*)(VtH + (ds * 16 + lm) * 64 + ((lg * 16) ^ vsw));

    // QK^T (A=K,B=Q): acc[j] = logit(q=lm, kv=kv0+sub*16+lg*4+j)
    #pragma unroll
    for (int sub = 0; sub < 2; ++sub) {
      f32x4 acc = (f32x4){0.f, 0.f, 0.f, 0.f};
      #pragma unroll
      for (int dc = 0; dc < 2; ++dc)
        acc = __builtin_amdgcn_mfma_f32_16x16x32_bf16(kf[sub * 2 + dc], qf[dc],
                                                      acc, 0, 0, 0);
      float pe[4];
      #pragma unroll
      for (int j = 0; j < 4; ++j) {
        float amc = m[sub][j] ? a[sub][j] * C : -1.8e8f;
        pe[j] = exp2f(fmaf(acc[j], C, amc));   // masked -> exact 0
        sum += pe[j];
      }
      uint2v u2;
      u2[0] = cvt_pk(pe[0], pe[1]); u2[1] = cvt_pk(pe[2], pe[3]);
      *(uint2v*)((char*)Ps + (p * 16 + lm) * 2048 +
                 (((kv0 + sub * 16 + lg * 4) * 2) ^ (lm << 4))) = u2;
    }
    // own-wave Ps RAW fence (rule #18)
    lgkm0();
    __builtin_amdgcn_sched_barrier(0);
    // PV: pf = P[q=lm][kv0+lg*8..+7]; same k-map as vf (kv-local lg*8+e)
    short8 pf = *(const short8*)((char*)Ps + (p * 16 + lm) * 2048 +
                                 (((kv0 + lg * 8) * 2) ^ (lm << 4)));
    #pragma unroll
    for (int ds = 0; ds < 4; ++ds)
      ctx[ds] = __builtin_amdgcn_mfma_f32_16x16x32_bf16(pf, vf[ds], ctx[ds], 0, 0, 0);
  };

  // ---- sweep: 16 chunks of 32 kv in this half (R6 barrier pattern) ----
  issueStage(kvb, skA, svA);
  loadAM(kvb, aA, mA);
  for (int c = 0; c < 16; c += 2) {
    int kv0 = kvb + c * 32;
    bar();                                 // staging buffers free
    writeStage(skA, svA);                  // counted-vmcnt wait on skA/svA
    issueStage(kv0 + 32, skB, svB);        // next chunk in flight
    loadAM(kv0 + 32, aB, mB);
    lgkm0(); bar();                        // staging visible; vm prefetch live
    compute(kv0, aA, mA);
    bar();
    writeStage(skB, svB);
    if (c < 14) { issueStage(kv0 + 64, skA, svA); loadAM(kv0 + 64, aA, mA); }
    lgkm0(); bar();
    compute(kv0 + 32, aB, mB);
  }

  // ---- merge halves ----
  sum += __shfl_xor(sum, 16);
  sum += __shfl_xor(sum, 32);
  __syncthreads();                         // all sweeps done; Ks/Vt regions dead

  float (*CtxS)[64] = (float(*)[64])(LDS + 65536);         // 32x64 f32 overlay
  float (*SumS)[2]  = (float(*)[2])(LDS + 65536 + 8192);   // 32x2 overlay
  if (l < 16) SumS[p * 16 + l][h] = sum;
  if (h == 1) {
    #pragma unroll
    for (int ds = 0; ds < 4; ++ds)
      #pragma unroll
      for (int j = 0; j < 4; ++j)
        CtxS[p * 16 + lg * 4 + j][ds * 16 + lm] = ctx[ds][j];
  }
  __syncthreads();

  float rcpv = 0.f;
  if (l < 16)
    rcpv = 1.0f / (SumS[p * 16 + l][0] + SumS[p * 16 + l][1]);

  if (h == 0) {
    #pragma unroll
    for (int ds = 0; ds < 4; ++ds)
      #pragma unroll
      for (int j = 0; j < 4; ++j) {
        int qr = lg * 4 + j;
        float rc = __shfl(rcpv, qr);
        float v = ctx[ds][j] + CtxS[p * 16 + qr][ds * 16 + lm];
        Octx[((size_t)bh * NSQ + q0 + p * 16 + qr) * ND + ds * 16 + lm] = v * rc;
      }
  }

  // ---- weights out: each wave stores its 16 rows x its 512-kv half ----
  float* Owp = Ow + (size_t)bh * NSQ * NSKV + (size_t)(q0 + p * 16) * NSKV + kvb;
  for (int r = 0; r < 16; ++r) {
    float rr = __shfl(rcpv, r);
    short8 pv = *(const short8*)((char*)Ps + (p * 16 + r) * 2048 +
                                 (((kvb + l * 8) * 2) ^ (r << 4)));
    f32x4 o1, o2;
    o1[0] = bf2f((unsigned short)pv[0]) * rr;
    o1[1] = bf2f((unsigned short)pv[1]) * rr;
    o1[2] = bf2f((unsigned short)pv[2]) * rr;
    o1[3] = bf2f((unsigned short)pv[3]) * rr;
    o2[0] = bf2f((unsigned short)pv[4]) * rr;
    o2[1] = bf2f((unsigned short)pv[5]) * rr;
    o2[2] = bf2f((unsigned short)pv[6]) * rr;
    o2[3] = bf2f((unsigned short)pv[7]) * rr;
    *(f32x4*)&Owp[(size_t)r * NSKV + l * 8]     = o1;
    *(f32x4*)&Owp[(size_t)r * NSKV + l * 8 + 4] = o2;
  }
}

extern "C" void kernel_launch(void* const* d_in, const int* in_sizes, int n_in,
                              void* d_out, int out_size, void* d_ws, size_t ws_size,
                              hipStream_t stream) {
  const float* Q = (const float*)d_in[0];
  const float* K = (const float*)d_in[1];
  const float* V = (const float*)d_in[2];
  const int*   M = (const int*)d_in[3];
  const float* A = (const float*)d_in[4];
  float* ctx = (float*)d_out;
  float* wts = ctx + (size_t)NB * NH * NSQ * ND;  // outputs: (context, weights)
  dim3 grid(NB * NH * (NSQ / 32));                // 2048 blocks
  attn_fused<<<grid, dim3(256), 0, stream>>>(Q, K, V, M, A, ctx, wts);
}